// Round 1
// baseline (1109.021 us; speedup 1.0000x reference)
//
#include <hip/hip_runtime.h>

typedef __attribute__((ext_vector_type(8))) short s8v;
typedef __attribute__((ext_vector_type(4))) float f4v;

#if __has_builtin(__builtin_amdgcn_exp2f)
#define EXP2(x) __builtin_amdgcn_exp2f(x)
#else
#define EXP2(x) exp2f(x)
#endif
#if __has_builtin(__builtin_amdgcn_rcpf)
#define RCP(x) __builtin_amdgcn_rcpf(x)
#else
#define RCP(x) (1.0f/(x))
#endif

#define LOG2E 1.4426950408889634f

__device__ __forceinline__ short f2bf(float f) {
    union { float f; unsigned u; } x; x.f = f;
    unsigned r = (x.u + 0x7FFFu + ((x.u >> 16) & 1u)) >> 16;
    return (short)r;
}

__device__ __forceinline__ float sigm(float x) {
    return RCP(1.0f + EXP2(-LOG2E * x));
}

// ---------------- weight prep: fp32 -> bf16 B-fragment layout ----------------
// WB1: [dir(2)][tile(32)][chunk(8)][lane(64)][8]  (L1: K = 128 x + 128 h, N=512)
// WB2: [dir(2)][tile(16)][chunk(10)][lane(64)][8] (L2: K = 256 y + 64 h, N=256)
// B-frag: lane l, elem j  <->  B[k = c*32 + (l>>4)*8 + j][n = tile*16 + (l&15)]
__global__ void prep_weights(const float* __restrict__ k1f, const float* __restrict__ r1f,
                             const float* __restrict__ k1b, const float* __restrict__ r1b,
                             const float* __restrict__ k2f, const float* __restrict__ r2f,
                             const float* __restrict__ k2b, const float* __restrict__ r2b,
                             short* __restrict__ WB1, short* __restrict__ WB2) {
    int idx = blockIdx.x * 256 + threadIdx.x;
    if (idx < 262144) {  // 2*32*8*64*8
        int j = idx & 7, l = (idx >> 3) & 63, c = (idx >> 9) & 7, n = (idx >> 12) & 31, d = (idx >> 17) & 1;
        int coln = n * 16 + (l & 15);
        int k = c * 32 + ((l >> 4) * 8) + j;
        const float* Wk = d ? k1b : k1f;
        const float* Wr = d ? r1b : r1f;
        float v = (c < 4) ? Wk[k * 512 + coln] : Wr[(k - 128) * 512 + coln];
        WB1[idx] = f2bf(v);
    }
    if (idx < 163840) {  // 2*16*10*64*8
        int d = idx / 81920, r0 = idx % 81920;
        int n = r0 / 5120, r1 = r0 % 5120;
        int c = r1 / 512, li = r1 % 512;
        int l = li >> 3, j = li & 7;
        int coln = n * 16 + (l & 15);
        int k = c * 32 + ((l >> 4) * 8) + j;
        const float* Wk = d ? k2b : k2f;
        const float* Wr = d ? r2b : r2f;
        float v = (k < 256) ? Wk[k * 256 + coln] : Wr[(k - 256) * 256 + coln];
        WB2[idx] = f2bf(v);
    }
}

// ---------------- embedding MLP branch (fp32, exact) ----------------
__global__ void embed_kernel(const int* __restrict__ inputA, const float* __restrict__ emb,
                             const float* __restrict__ w1, const float* __restrict__ b1,
                             const float* __restrict__ w2, const float* __restrict__ b2,
                             const float* __restrict__ w3, const float* __restrict__ b3,
                             float* __restrict__ xe) {
    __shared__ float row[600];
    __shared__ float h1[256];
    __shared__ float h2[128];
    int b = blockIdx.x, t = threadIdx.x;
    if (t < 200) {
        int idx = inputA[b * 200 + t];
        row[t * 3 + 0] = emb[idx * 3 + 0];
        row[t * 3 + 1] = emb[idx * 3 + 1];
        row[t * 3 + 2] = emb[idx * 3 + 2];
    }
    __syncthreads();
    float a = b1[t];
    for (int k = 0; k < 600; k++) a += row[k] * w1[k * 256 + t];
    h1[t] = fmaxf(a, 0.f);
    __syncthreads();
    if (t < 128) {
        float a2 = b2[t];
        for (int k = 0; k < 256; k++) a2 += h1[k] * w2[k * 128 + t];
        h2[t] = fmaxf(a2, 0.f);
    }
    __syncthreads();
    if (t < 64) {
        float a3 = b3[t];
        for (int k = 0; k < 128; k++) a3 += h2[k] * w3[k * 64 + t];
        xe[b * 64 + t] = fmaxf(a3, 0.f);
    }
}

// ---------------- LSTM layer 1 (F=128, H=128, both dirs), fused x@Wk ----------------
// grid: 32 blocks = 16 batch-tiles x 2 dirs; 512 threads = 8 waves.
// wave w owns gate-quads of units [16w, 16w+16): N-tiles {w, 8+w, 16+w, 24+w}.
// y output (for L2) stored in A-frag layout: [btile][t][chunk(8)][lane(64)][8] bf16;
//   dir 0 writes chunks 0-3 (features 0..127), dir 1 chunks 4-7 (128..255).
__global__ __launch_bounds__(512, 2) void lstm1_kernel(
        const float* __restrict__ x, const short* __restrict__ WB1,
        const float* __restrict__ bbf, const float* __restrict__ bbb,
        short* __restrict__ yfr) {
    __shared__ short hfrag[4 * 512];
    __shared__ short xfrag[2][4 * 512];
    const int tid = threadIdx.x;
    const int lane = tid & 63, w = tid >> 6;
    const int btile = blockIdx.x & 15, dir = blockIdx.x >> 4;
    const int b0 = btile << 4;
    const int col = lane & 15, q = lane >> 4;
    const int u = (w << 4) + col;

    // weights into registers: 4 tiles x 8 chunks x 16B = 128 VGPRs
    s8v wf[4][8];
#pragma unroll
    for (int ti = 0; ti < 4; ti++) {
        const int tile = w + ti * 8;
#pragma unroll
        for (int c = 0; c < 8; c++) {
            const short* p = WB1 + ((((dir * 32 + tile) * 8) + c) * 64 + lane) * 8;
            wf[ti][c] = *(const s8v*)p;
        }
    }
    const float* bb = dir ? bbb : bbf;
    const float bi = bb[u], bfg = bb[128 + u], bc = bb[256 + u], bo = bb[384 + u];

    float cst[4] = {0.f, 0.f, 0.f, 0.f};
    float hl[4] = {0.f, 0.f, 0.f, 0.f};
    for (int i = tid; i < 4 * 512; i += 512) hfrag[i] = 0;
    if (w < 4) {  // preload x frag for step 0 (wave w = chunk w)
        const int t0 = dir ? 511 : 0;
        const float* xp = x + (((b0 + col) * 512 + t0) * 128) + (w * 32 + q * 8);
        const f4v* xp4 = (const f4v*)xp;
        f4v va = xp4[0], vb = xp4[1];
        short* dst = &xfrag[0][(w * 64 + lane) * 8];
#pragma unroll
        for (int j = 0; j < 4; j++) { dst[j] = f2bf(va[j]); dst[4 + j] = f2bf(vb[j]); }
    }
    __syncthreads();

    // h-frag write slot: chunk=(u>>5), lane'=(m | phase<<4), byte j=(u&7)
    const int hidx = (w >> 1) * 512 + ((u >> 3) & 3) * 128 + (u & 7);

    for (int s = 0; s < 512; s++) {
        const int buf = s & 1;
        s8v ax[4], ah[4];
#pragma unroll
        for (int c = 0; c < 4; c++) {
            ax[c] = *(const s8v*)&xfrag[buf][(c * 64 + lane) * 8];
            ah[c] = *(const s8v*)&hfrag[(c * 64 + lane) * 8];
        }
        // store h(s-1) to y (waves 4-7, one chunk each; coalesced 1KB/wave)
        if (w >= 4 && s > 0) {
            const int tprev = dir ? (512 - s) : (s - 1);
            const int c = w - 4;
            s8v hv = (w == 4) ? ah[0] : (w == 5) ? ah[1] : (w == 6) ? ah[2] : ah[3];
            short* yp = yfr + (((size_t)(btile * 512 + tprev) * 8) + dir * 4 + c) * 512 + lane * 8;
            *(s8v*)yp = hv;
        }
        // prefetch x(s+1) into regs (waves 0-3), latency hidden behind MFMA
        f4v pva, pvb;
        const bool pf = (w < 4) && (s < 511);
        if (pf) {
            const int tn = dir ? (510 - s) : (s + 1);
            const float* xp = x + (((b0 + col) * 512 + tn) * 128) + (w * 32 + q * 8);
            const f4v* xp4 = (const f4v*)xp;
            pva = xp4[0]; pvb = xp4[1];
        }
        f4v acc[4];
#pragma unroll
        for (int ti = 0; ti < 4; ti++) { f4v z = {0.f, 0.f, 0.f, 0.f}; acc[ti] = z; }
#pragma unroll
        for (int c = 0; c < 4; c++) {
#pragma unroll
            for (int ti = 0; ti < 4; ti++)
                acc[ti] = __builtin_amdgcn_mfma_f32_16x16x32_bf16(ax[c], wf[ti][c], acc[ti], 0, 0, 0);
        }
#pragma unroll
        for (int c = 0; c < 4; c++) {
#pragma unroll
            for (int ti = 0; ti < 4; ti++)
                acc[ti] = __builtin_amdgcn_mfma_f32_16x16x32_bf16(ah[c], wf[ti][4 + c], acc[ti], 0, 0, 0);
        }
        // gates: acc[0]=i, acc[1]=f, acc[2]=cc, acc[3]=o; reg r <-> batch m=q*4+r
#pragma unroll
        for (int r = 0; r < 4; r++) {
            float gi = acc[0][r] + bi;
            float gf = acc[1][r] + bfg;
            float gc = acc[2][r] + bc;
            float go = acc[3][r] + bo;
            float iv = sigm(gi), fv = sigm(gf), ov = sigm(go);
            float ccv = fmaxf(gc, 0.f);
            cst[r] = fv * cst[r] + iv * ccv;
            hl[r] = ov * fmaxf(cst[r], 0.f);
        }
        __syncthreads();  // all frag reads done before overwrite
#pragma unroll
        for (int r = 0; r < 4; r++)
            hfrag[hidx + ((q * 4 + r) << 3)] = f2bf(hl[r]);
        if (pf) {
            short* dst = &xfrag[buf ^ 1][(w * 64 + lane) * 8];
#pragma unroll
            for (int j = 0; j < 4; j++) { dst[j] = f2bf(pva[j]); dst[4 + j] = f2bf(pvb[j]); }
        }
        __syncthreads();  // h(s) + x(s+1) visible
    }
    // final y store: h(511)
    if (w >= 4) {
        const int c = w - 4;
        const int tlast = dir ? 0 : 511;
        s8v hv = *(const s8v*)&hfrag[(c * 64 + lane) * 8];
        short* yp = yfr + (((size_t)(btile * 512 + tlast) * 8) + dir * 4 + c) * 512 + lane * 8;
        *(s8v*)yp = hv;
    }
}

// ---------------- LSTM layer 2 (F=256, H=64, both dirs), returns final h ----------------
// grid: 32 blocks; 256 threads = 4 waves. wave w: N-tiles {w, 4+w, 8+w, 12+w} = units [16w,16w+16).
__global__ __launch_bounds__(256, 1) void lstm2_kernel(
        const short* __restrict__ yfr, const short* __restrict__ WB2,
        const float* __restrict__ bbf, const float* __restrict__ bbb,
        float* __restrict__ h2o) {
    __shared__ short hfrag[2 * 512];
    __shared__ short yfragL[2][8 * 512];
    const int tid = threadIdx.x;
    const int lane = tid & 63, w = tid >> 6;
    const int btile = blockIdx.x & 15, dir = blockIdx.x >> 4;
    const int b0 = btile << 4;
    const int col = lane & 15, q = lane >> 4;
    const int u = (w << 4) + col;

    s8v wf[4][10];  // 160 VGPRs
#pragma unroll
    for (int ti = 0; ti < 4; ti++) {
        const int tile = w + ti * 4;
#pragma unroll
        for (int c = 0; c < 10; c++) {
            const short* p = WB2 + ((((dir * 16 + tile) * 10) + c) * 64 + lane) * 8;
            wf[ti][c] = *(const s8v*)p;
        }
    }
    const float* bb = dir ? bbb : bbf;
    const float bi = bb[u], bfg = bb[64 + u], bc = bb[128 + u], bo = bb[192 + u];

    float cst[4] = {0.f, 0.f, 0.f, 0.f};
    float hl[4] = {0.f, 0.f, 0.f, 0.f};
    for (int i = tid; i < 1024; i += 256) hfrag[i] = 0;
    {   // preload y frags for step 0: wave w loads chunks 2w, 2w+1 (coalesced)
        const int t0 = dir ? 511 : 0;
#pragma unroll
        for (int cc = 0; cc < 2; cc++) {
            const int c = 2 * w + cc;
            const short* yp = yfr + (((size_t)(btile * 512 + t0) * 8) + c) * 512 + lane * 8;
            *(s8v*)&yfragL[0][(c * 64 + lane) * 8] = *(const s8v*)yp;
        }
    }
    __syncthreads();

    const int hidx = (w >> 1) * 512 + ((u >> 3) & 3) * 128 + (u & 7);

    for (int s = 0; s < 512; s++) {
        const int buf = s & 1;
        s8v ay[8], ahh[2];
#pragma unroll
        for (int c = 0; c < 8; c++) ay[c] = *(const s8v*)&yfragL[buf][(c * 64 + lane) * 8];
#pragma unroll
        for (int c = 0; c < 2; c++) ahh[c] = *(const s8v*)&hfrag[(c * 64 + lane) * 8];

        s8v pre0, pre1;
        const bool pf = (s < 511);
        if (pf) {
            const int tn = dir ? (510 - s) : (s + 1);
            const short* yp0 = yfr + (((size_t)(btile * 512 + tn) * 8) + 2 * w) * 512 + lane * 8;
            pre0 = *(const s8v*)yp0;
            pre1 = *(const s8v*)(yp0 + 512);
        }
        f4v acc[4];
#pragma unroll
        for (int ti = 0; ti < 4; ti++) { f4v z = {0.f, 0.f, 0.f, 0.f}; acc[ti] = z; }
#pragma unroll
        for (int c = 0; c < 8; c++) {
#pragma unroll
            for (int ti = 0; ti < 4; ti++)
                acc[ti] = __builtin_amdgcn_mfma_f32_16x16x32_bf16(ay[c], wf[ti][c], acc[ti], 0, 0, 0);
        }
#pragma unroll
        for (int c = 0; c < 2; c++) {
#pragma unroll
            for (int ti = 0; ti < 4; ti++)
                acc[ti] = __builtin_amdgcn_mfma_f32_16x16x32_bf16(ahh[c], wf[ti][8 + c], acc[ti], 0, 0, 0);
        }
#pragma unroll
        for (int r = 0; r < 4; r++) {
            float gi = acc[0][r] + bi;
            float gf = acc[1][r] + bfg;
            float gc = acc[2][r] + bc;
            float go = acc[3][r] + bo;
            float iv = sigm(gi), fv = sigm(gf), ov = sigm(go);
            float ccv = fmaxf(gc, 0.f);
            cst[r] = fv * cst[r] + iv * ccv;
            hl[r] = ov * fmaxf(cst[r], 0.f);
        }
        __syncthreads();
#pragma unroll
        for (int r = 0; r < 4; r++)
            hfrag[hidx + ((q * 4 + r) << 3)] = f2bf(hl[r]);
        if (pf) {
            *(s8v*)&yfragL[buf ^ 1][((2 * w) * 64 + lane) * 8] = pre0;
            *(s8v*)&yfragL[buf ^ 1][((2 * w + 1) * 64 + lane) * 8] = pre1;
        }
        __syncthreads();
    }
#pragma unroll
    for (int r = 0; r < 4; r++)
        h2o[((dir * 256) + b0 + q * 4 + r) * 64 + u] = hl[r];
}

// ---------------- final heads (fp32) ----------------
__global__ void heads_kernel(const float* __restrict__ xe, const float* __restrict__ h2o,
                             const float* __restrict__ wz1, const float* __restrict__ bz1,
                             const float* __restrict__ wz2, const float* __restrict__ bz2,
                             const float* __restrict__ wt1, const float* __restrict__ bt1,
                             const float* __restrict__ wt2, const float* __restrict__ bt2,
                             float* __restrict__ out) {
    int b = threadIdx.x;  // 256 threads, 1 block
    float cz0 = bz1[0], cz1 = bz1[1], ct0 = bt1[0], ct1 = bt1[1];
    for (int k = 0; k < 192; k++) {
        float v = (k < 64) ? xe[b * 64 + k]
                : (k < 128) ? h2o[b * 64 + (k - 64)]
                            : h2o[(256 + b) * 64 + (k - 128)];
        cz0 += v * wz1[k * 2 + 0];
        cz1 += v * wz1[k * 2 + 1];
        ct0 += v * wt1[k * 2 + 0];
        ct1 += v * wt1[k * 2 + 1];
    }
    cz0 = fmaxf(cz0, 0.f); cz1 = fmaxf(cz1, 0.f);
    ct0 = fmaxf(ct0, 0.f); ct1 = fmaxf(ct1, 0.f);
    out[b] = cz0 * wz2[0] + cz1 * wz2[1] + bz2[0];
    out[256 + b] = ct0 * wt2[0] + ct1 * wt2[1] + bt2[0];
}

extern "C" void kernel_launch(void* const* d_in, const int* in_sizes, int n_in,
                              void* d_out, int out_size, void* d_ws, size_t ws_size,
                              hipStream_t stream) {
    const int*   inputA = (const int*)d_in[0];
    const float* inputB = (const float*)d_in[1];
    const float* emb = (const float*)d_in[2];
    const float* w1  = (const float*)d_in[3];
    const float* b1  = (const float*)d_in[4];
    const float* w2  = (const float*)d_in[5];
    const float* b2  = (const float*)d_in[6];
    const float* w3  = (const float*)d_in[7];
    const float* b3  = (const float*)d_in[8];
    const float* k1f = (const float*)d_in[9];
    const float* r1f = (const float*)d_in[10];
    const float* bb1f= (const float*)d_in[11];
    const float* k1b = (const float*)d_in[12];
    const float* r1b = (const float*)d_in[13];
    const float* bb1b= (const float*)d_in[14];
    const float* k2f = (const float*)d_in[15];
    const float* r2f = (const float*)d_in[16];
    const float* bb2f= (const float*)d_in[17];
    const float* k2b = (const float*)d_in[18];
    const float* r2b = (const float*)d_in[19];
    const float* bb2b= (const float*)d_in[20];
    const float* wz1 = (const float*)d_in[21];
    const float* bz1 = (const float*)d_in[22];
    const float* wz2 = (const float*)d_in[23];
    const float* bz2 = (const float*)d_in[24];
    const float* wt1 = (const float*)d_in[25];
    const float* bt1 = (const float*)d_in[26];
    const float* wt2 = (const float*)d_in[27];
    const float* bt2 = (const float*)d_in[28];

    char* ws = (char*)d_ws;
    short* WB1 = (short*)(ws);                                  // 512 KB
    short* WB2 = (short*)(ws + 524288);                         // 320 KB
    short* yfr = (short*)(ws + 1048576);                        // 64 MB bf16 frags
    float* xe  = (float*)(ws + 1048576 + 67108864);             // 64 KB
    float* h2o = (float*)(ws + 1048576 + 67108864 + 65536);     // 128 KB
    float* out = (float*)d_out;

    prep_weights<<<1024, 256, 0, stream>>>(k1f, r1f, k1b, r1b, k2f, r2f, k2b, r2b, WB1, WB2);
    embed_kernel<<<256, 256, 0, stream>>>(inputA, emb, w1, b1, w2, b2, w3, b3, xe);
    lstm1_kernel<<<32, 512, 0, stream>>>(inputB, WB1, bb1f, bb1b, yfr);
    lstm2_kernel<<<32, 256, 0, stream>>>(yfr, WB2, bb2f, bb2b, h2o);
    heads_kernel<<<1, 256, 0, stream>>>(xe, h2o, wz1, bz1, wz2, bz2, wt1, bt1, wt2, bt2, out);
}